// Round 21
// baseline (345.803 us; speedup 1.0000x reference)
//
#include <hip/hip_runtime.h>

#define Hh 64
#define Ww 64
#define Cc 512
#define Bb 16
#define NTOK (1 + Hh * Ww)   // 4097
#define TW 8                 // output pixels per thread along w
#define TH 4                 // output pixels per thread along h

typedef float v2f __attribute__((ext_vector_type(2)));

// ---------------------------------------------------------------------------
// Prep kernel (unchanged): combine w7 + padded w5 + padded w3 + identity into
// one effective 7x7 kernel per channel, stored TRANSPOSED [tap][channel].
// Combine biases, copy cls tokens through.
// ---------------------------------------------------------------------------
__global__ void ppeg_prep(const float* __restrict__ w7, const float* __restrict__ b7,
                          const float* __restrict__ w5, const float* __restrict__ b5,
                          const float* __restrict__ w3, const float* __restrict__ b3,
                          const float* __restrict__ x, float* __restrict__ wt,
                          float* __restrict__ beff, float* __restrict__ out) {
    int idx = blockIdx.x * blockDim.x + threadIdx.x;
    if (idx < Cc * 49) {
        int c = idx / 49, t = idx % 49;
        int r = t / 7, s = t % 7;
        float v = w7[idx];
        if (r >= 1 && r <= 5 && s >= 1 && s <= 5) v += w5[c * 25 + (r - 1) * 5 + (s - 1)];
        if (r >= 2 && r <= 4 && s >= 2 && s <= 4) v += w3[c * 9 + (r - 2) * 3 + (s - 2)];
        if (t == 24) v += 1.0f;               // identity (center tap)
        wt[t * Cc + c] = v;                   // transposed store
    }
    if (idx < Cc) beff[idx] = b7[idx] + b5[idx] + b3[idx];
    if (idx < Bb * Cc) {
        int b = idx / Cc, c = idx % Cc;
        size_t o = (size_t)b * NTOK * Cc + c;
        out[o] = x[o];                        // cls token pass-through
    }
}

// ---------------------------------------------------------------------------
// Conv kernel v22 = v10 VERBATIM (the stable 104us / 64-VGPR body) with ONLY
// the wave->tile index remap: ty splits along W, not H.
//
// v21 post-mortem: the remap works at the cache level (FETCH 66.5 MB =
// session low, proving coincident-read dedup is real) but pairing it with
// launch_bounds(256,1) + non-uniform asm branches ballooned VGPR to 180,
// occupancy to 10.8%, and time to 150us. v22 strips every allocator
// trigger: plain v2f loads (v18 proved asm batching worth only +4%),
// launch_bounds(256,2) (always yields 64-80 VGPR on this body), v10's
// exact loop structure. Per-thread instruction stream is IDENTICAL to
// v10 -- only the ADDRESSES sibling waves read change: block = 4 output
// rows x 32 px; all 4 waves stream the same 10 input rows in lockstep k
// with 6-px w-overlap issued within cycles -> same-CU L1 hits; effective
// block read-amp 4.375x -> ~2.97x.
//
// GATES: VGPR ~64, WRITE ~131 MB. Prediction: FETCH -> 70-100 MB (v21's
// dedup fingerprint), conv 104 -> 82-92us. If VGPR=64 and time flat ~104:
// all levers exhausted cleanly; kernel is at the vector-path throughput
// ceiling (~7 TB/s effective > 6.29 demonstrated) -> declare ROOFLINE
// next round, keeping v18.
//
// Kept: v2f lanes, LDS tap slab, chunked XCD swizzle, nontemporal stores,
// 256-thread blocks, fp contract (v_pk_fma_f32).
// ---------------------------------------------------------------------------
__global__ __launch_bounds__(256, 2)
void ppeg_conv(const float* __restrict__ x, const float* __restrict__ wt,
               const float* __restrict__ beff, float* __restrict__ out) {
#pragma clang fp contract(fast)
    const int tx = threadIdx.x;        // channel-pair lane 0..63
    const int ty = threadIdx.y;        // w-subtile 0..3 (wave-uniform)

    // --- chunked XCD swizzle (XCD = linear id % 8, x fastest; bijective) ----
    const int L     = blockIdx.x + 32 * (blockIdx.y + 4 * blockIdx.z); // 0..2047
    const int g_lin = (L & 7) * 256 + (L >> 3);
    const int sp    = g_lin & 31;      // spatial block 0..31 within group
    const int g     = g_lin >> 5;      // 0..63 : (cblk, b) group
    const int cb    = (g & 3) * 128;
    const int b     = g >> 2;
    // ------------------------------------------------------------------------

    const int wblk  = sp & 1;          // 0..1 : 32-px halves
    const int hblk  = sp >> 1;         // 0..15 : 4-row strips
    const int oh0   = hblk * TH;       // block's 4 output rows (all waves)
    const int wbase = wblk * 32 + ty * TW;   // this wave's 8 output pixels

    // Stage the block's 49x128 tap slab into LDS (once), coalesced.
    __shared__ float taps[49][128];
    const int tid = ty * 64 + tx;
    for (int idx = tid; idx < 49 * 128; idx += 256) {
        taps[idx >> 7][idx & 127] = wt[(idx >> 7) * Cc + cb + (idx & 127)];
    }
    __syncthreads();

    const int c0 = cb + 2 * tx;
    const float* xb = x + ((size_t)b * NTOK + 1) * Cc + c0;  // pixel (0,0)

    const v2f bias = *(const v2f*)&beff[c0];
    v2f acc[TH][TW];
#pragma unroll
    for (int o = 0; o < TH; ++o)
#pragma unroll
        for (int j = 0; j < TW; ++j) acc[o][j] = bias;

    const bool interior = (wbase != 0) && (wbase != Ww - TW);  // wave-uniform

    // All 4 waves stream the same input rows k = 0..9 in lockstep; wave's
    // w-window is wbase-3..wbase+10. Row k feeds output rows o in [k-6, k].
#pragma unroll
    for (int k = 0; k < TH + 6; ++k) {
        const int ir = oh0 + k - 3;
        if (ir >= 0 && ir < Hh) {              // block-uniform
            const float* xrow = xb + (size_t)ir * (Ww * Cc);
            v2f v[TW + 6];
            if (interior) {
#pragma unroll
                for (int j = 0; j < TW + 6; ++j)
                    v[j] = *(const v2f*)(xrow + (size_t)(wbase - 3 + j) * Cc);
            } else {
#pragma unroll
                for (int j = 0; j < TW + 6; ++j) {
                    const int wc = wbase + j - 3;
                    if (wc >= 0 && wc < Ww)
                        v[j] = *(const v2f*)(xrow + (size_t)wc * Cc);
                    else {
                        v[j].x = 0.0f; v[j].y = 0.0f;
                    }
                }
            }
#pragma unroll
            for (int o = 0; o < TH; ++o) {
                if (o > k || o < k - 6) continue;   // static after unroll
                const int r = k - o;
#pragma unroll
                for (int s = 0; s < 7; ++s) {
                    const v2f tp = *(const v2f*)&taps[r * 7 + s][2 * tx];
#pragma unroll
                    for (int j = 0; j < TW; ++j)
                        acc[o][j] = tp * v[j + s] + acc[o][j];   // v_pk_fma_f32
                }
            }
        }
    }

#pragma unroll
    for (int o = 0; o < TH; ++o) {
        float* orow = out + ((size_t)b * NTOK + 1 + (size_t)(oh0 + o) * Ww + wbase) * Cc + c0;
#pragma unroll
        for (int j = 0; j < TW; ++j)
            __builtin_nontemporal_store(acc[o][j], (v2f*)(orow + (size_t)j * Cc));
    }
}

extern "C" void kernel_launch(void* const* d_in, const int* in_sizes, int n_in,
                              void* d_out, int out_size, void* d_ws, size_t ws_size,
                              hipStream_t stream) {
    const float* x  = (const float*)d_in[0];
    const float* w7 = (const float*)d_in[1];
    const float* b7 = (const float*)d_in[2];
    const float* w5 = (const float*)d_in[3];
    const float* b5 = (const float*)d_in[4];
    const float* w3 = (const float*)d_in[5];
    const float* b3 = (const float*)d_in[6];
    float* out = (float*)d_out;

    float* wt   = (float*)d_ws;          // 49*Cc floats, transposed [tap][channel]
    float* beff = wt + 49 * Cc;          // Cc floats

    ppeg_prep<<<(Cc * 49 + 255) / 256, 256, 0, stream>>>(w7, b7, w5, b5, w3, b3,
                                                         x, wt, beff, out);

    // (2 wblk x 16 hblk) x 4 cblk x 16 b = 2048 blocks of 256 threads.
    dim3 grid(32, Cc / 128, Bb);
    dim3 block(64, 4);
    ppeg_conv<<<grid, block, 0, stream>>>(x, wt, beff, out);
}

// Round 22
// 335.028 us; speedup vs baseline: 1.0322x; 1.0322x over previous
//
#include <hip/hip_runtime.h>

#define Hh 64
#define Ww 64
#define Cc 512
#define Bb 16
#define NTOK (1 + Hh * Ww)   // 4097
#define TW 8                 // output pixels per thread along w
#define TH 4                 // output pixels per thread along h

typedef float v2f __attribute__((ext_vector_type(2)));

// ---------------------------------------------------------------------------
// Prep kernel (unchanged): combine w7 + padded w5 + padded w3 + identity into
// one effective 7x7 kernel per channel, stored TRANSPOSED [tap][channel].
// Combine biases, copy cls tokens through.
// ---------------------------------------------------------------------------
__global__ void ppeg_prep(const float* __restrict__ w7, const float* __restrict__ b7,
                          const float* __restrict__ w5, const float* __restrict__ b5,
                          const float* __restrict__ w3, const float* __restrict__ b3,
                          const float* __restrict__ x, float* __restrict__ wt,
                          float* __restrict__ beff, float* __restrict__ out) {
    int idx = blockIdx.x * blockDim.x + threadIdx.x;
    if (idx < Cc * 49) {
        int c = idx / 49, t = idx % 49;
        int r = t / 7, s = t % 7;
        float v = w7[idx];
        if (r >= 1 && r <= 5 && s >= 1 && s <= 5) v += w5[c * 25 + (r - 1) * 5 + (s - 1)];
        if (r >= 2 && r <= 4 && s >= 2 && s <= 4) v += w3[c * 9 + (r - 2) * 3 + (s - 2)];
        if (t == 24) v += 1.0f;               // identity (center tap)
        wt[t * Cc + c] = v;                   // transposed store
    }
    if (idx < Cc) beff[idx] = b7[idx] + b5[idx] + b3[idx];
    if (idx < Bb * Cc) {
        int b = idx / Cc, c = idx % Cc;
        size_t o = (size_t)b * NTOK * Cc + c;
        out[o] = x[o];                        // cls token pass-through
    }
}

// ---------------------------------------------------------------------------
// Conv kernel v23 = v22 + readfirstlane(wbase): the dedup remap with the
// register balloon surgically removed.
//
// v22 post-mortem (disasm-level): wbase depended on threadIdx.y -> VGPR in
// the compiler's eyes -> (a) the interior/edge branch became DIVERGENT and
// was if-converted, keeping both paths' 28-reg windows live; (b) all 14
// window addresses materialized as per-lane 64-bit VGPR pairs. VGPR 64 ->
// 128 + 200 MB scratch. v10's 64-VGPR codegen relied on wbase being
// SGPR-resident (scalar branch, scalar-base addressing).
//
// Fix: block is (64,4) -- each wave IS one ty slice, so wbase is wave-
// uniform by construction. __builtin_amdgcn_readfirstlane(wbase) moves it
// to an SGPR, restoring v10's scalar branch + addressing byte-for-byte.
// This finally runs the clean A/B: per-thread instruction stream identical
// to v10 (104us, 64 VGPR); only sibling-wave ADDRESSES change -- all 4
// waves stream the same 10 input rows in lockstep with 6-px w-overlap ->
// same-CU L1 dedup (mechanism already proven at cache level: v21/v22 FETCH
// dropped to 66-100 MB range despite spill noise).
//
// GATES: VGPR 64-80 (>=100 = void -> restore v18 + declare); WRITE ~131 MB.
// Prediction: FETCH 70-100 MB, conv 82-95us. Flat ~104 with clean gates ->
// dedup doesn't reach the clock -> ROOFLINE verdict next round with v18.
//
// Kept: v2f lanes, LDS tap slab, chunked XCD swizzle, nontemporal stores,
// 256-thread blocks, fp contract (v_pk_fma_f32).
// ---------------------------------------------------------------------------
__global__ __launch_bounds__(256, 2)
void ppeg_conv(const float* __restrict__ x, const float* __restrict__ wt,
               const float* __restrict__ beff, float* __restrict__ out) {
#pragma clang fp contract(fast)
    const int tx = threadIdx.x;        // channel-pair lane 0..63
    const int ty = threadIdx.y;        // w-subtile 0..3 (wave-uniform)

    // --- chunked XCD swizzle (XCD = linear id % 8, x fastest; bijective) ----
    const int L     = blockIdx.x + 32 * (blockIdx.y + 4 * blockIdx.z); // 0..2047
    const int g_lin = (L & 7) * 256 + (L >> 3);
    const int sp    = g_lin & 31;      // spatial block 0..31 within group
    const int g     = g_lin >> 5;      // 0..63 : (cblk, b) group
    const int cb    = (g & 3) * 128;
    const int b     = g >> 2;
    // ------------------------------------------------------------------------

    const int wblk  = sp & 1;          // 0..1 : 32-px halves
    const int hblk  = sp >> 1;         // 0..15 : 4-row strips
    const int oh0   = hblk * TH;       // block's 4 output rows (all waves)
    // Wave-uniform by construction (block 64x4: wave == ty slice); force it
    // into an SGPR so branches stay scalar and addressing stays scalar-base.
    const int wbase = __builtin_amdgcn_readfirstlane(wblk * 32 + ty * TW);

    // Stage the block's 49x128 tap slab into LDS (once), coalesced.
    __shared__ float taps[49][128];
    const int tid = ty * 64 + tx;
    for (int idx = tid; idx < 49 * 128; idx += 256) {
        taps[idx >> 7][idx & 127] = wt[(idx >> 7) * Cc + cb + (idx & 127)];
    }
    __syncthreads();

    const int c0 = cb + 2 * tx;
    const float* xb = x + ((size_t)b * NTOK + 1) * Cc + c0;  // pixel (0,0)

    const v2f bias = *(const v2f*)&beff[c0];
    v2f acc[TH][TW];
#pragma unroll
    for (int o = 0; o < TH; ++o)
#pragma unroll
        for (int j = 0; j < TW; ++j) acc[o][j] = bias;

    const bool interior = (wbase != 0) && (wbase != Ww - TW);  // scalar branch

    // All 4 waves stream the same input rows k = 0..9 in lockstep; wave's
    // w-window is wbase-3..wbase+10. Row k feeds output rows o in [k-6, k].
#pragma unroll
    for (int k = 0; k < TH + 6; ++k) {
        const int ir = oh0 + k - 3;
        if (ir >= 0 && ir < Hh) {              // block-uniform
            const float* xrow = xb + (size_t)ir * (Ww * Cc);
            v2f v[TW + 6];
            if (interior) {
#pragma unroll
                for (int j = 0; j < TW + 6; ++j)
                    v[j] = *(const v2f*)(xrow + (size_t)(wbase - 3 + j) * Cc);
            } else {
#pragma unroll
                for (int j = 0; j < TW + 6; ++j) {
                    const int wc = wbase + j - 3;
                    if (wc >= 0 && wc < Ww)
                        v[j] = *(const v2f*)(xrow + (size_t)wc * Cc);
                    else {
                        v[j].x = 0.0f; v[j].y = 0.0f;
                    }
                }
            }
#pragma unroll
            for (int o = 0; o < TH; ++o) {
                if (o > k || o < k - 6) continue;   // static after unroll
                const int r = k - o;
#pragma unroll
                for (int s = 0; s < 7; ++s) {
                    const v2f tp = *(const v2f*)&taps[r * 7 + s][2 * tx];
#pragma unroll
                    for (int j = 0; j < TW; ++j)
                        acc[o][j] = tp * v[j + s] + acc[o][j];   // v_pk_fma_f32
                }
            }
        }
    }

#pragma unroll
    for (int o = 0; o < TH; ++o) {
        float* orow = out + ((size_t)b * NTOK + 1 + (size_t)(oh0 + o) * Ww + wbase) * Cc + c0;
#pragma unroll
        for (int j = 0; j < TW; ++j)
            __builtin_nontemporal_store(acc[o][j], (v2f*)(orow + (size_t)j * Cc));
    }
}

extern "C" void kernel_launch(void* const* d_in, const int* in_sizes, int n_in,
                              void* d_out, int out_size, void* d_ws, size_t ws_size,
                              hipStream_t stream) {
    const float* x  = (const float*)d_in[0];
    const float* w7 = (const float*)d_in[1];
    const float* b7 = (const float*)d_in[2];
    const float* w5 = (const float*)d_in[3];
    const float* b5 = (const float*)d_in[4];
    const float* w3 = (const float*)d_in[5];
    const float* b3 = (const float*)d_in[6];
    float* out = (float*)d_out;

    float* wt   = (float*)d_ws;          // 49*Cc floats, transposed [tap][channel]
    float* beff = wt + 49 * Cc;          // Cc floats

    ppeg_prep<<<(Cc * 49 + 255) / 256, 256, 0, stream>>>(w7, b7, w5, b5, w3, b3,
                                                         x, wt, beff, out);

    // (2 wblk x 16 hblk) x 4 cblk x 16 b = 2048 blocks of 256 threads.
    dim3 grid(32, Cc / 128, Bb);
    dim3 block(64, 4);
    ppeg_conv<<<grid, block, 0, stream>>>(x, wt, beff, out);
}

// Round 23
// 267.246 us; speedup vs baseline: 1.2939x; 1.2536x over previous
//
#include <hip/hip_runtime.h>

#define Hh 64
#define Ww 64
#define Cc 512
#define Bb 16
#define NTOK (1 + Hh * Ww)   // 4097
#define TW 8                 // output pixels per thread along w
#define TH 4                 // output pixels per thread along h

typedef float v2f __attribute__((ext_vector_type(2)));

// ---------------------------------------------------------------------------
// Prep kernel: combine w7 + padded w5 + padded w3 + identity into one
// effective 7x7 kernel per channel, stored TRANSPOSED [tap][channel].
// Combine biases, copy cls tokens through.
// ---------------------------------------------------------------------------
__global__ void ppeg_prep(const float* __restrict__ w7, const float* __restrict__ b7,
                          const float* __restrict__ w5, const float* __restrict__ b5,
                          const float* __restrict__ w3, const float* __restrict__ b3,
                          const float* __restrict__ x, float* __restrict__ wt,
                          float* __restrict__ beff, float* __restrict__ out) {
    int idx = blockIdx.x * blockDim.x + threadIdx.x;
    if (idx < Cc * 49) {
        int c = idx / 49, t = idx % 49;
        int r = t / 7, s = t % 7;
        float v = w7[idx];
        if (r >= 1 && r <= 5 && s >= 1 && s <= 5) v += w5[c * 25 + (r - 1) * 5 + (s - 1)];
        if (r >= 2 && r <= 4 && s >= 2 && s <= 4) v += w3[c * 9 + (r - 2) * 3 + (s - 2)];
        if (t == 24) v += 1.0f;               // identity (center tap)
        wt[t * Cc + c] = v;                   // transposed store
    }
    if (idx < Cc) beff[idx] = b7[idx] + b5[idx] + b3[idx];
    if (idx < Bb * Cc) {
        int b = idx / Cc, c = idx % Cc;
        size_t o = (size_t)b * NTOK * Cc + c;
        out[o] = x[o];                        // cls token pass-through
    }
}

// ---------------------------------------------------------------------------
// Conv kernel: SESSION-BEST (v18, 99.5us conv / 268.7us bench), restored.
//
// Structure: TH=4 x TW=8 tile per thread, v2f channel-pair lanes, LDS tap
// slab, chunked XCD swizzle, nontemporal stores, and the atomic inline-asm
// batch window load: 14 global_load_dwordx2 via 4 base pointers (byte
// offsets in {-4096,-2048,0,+2048}) + ONE s_waitcnt vmcnt(0) per row.
// Measured: 64 VGPR, WRITE exactly 131 MB (zero scratch), FETCH ~122 MB.
//
// Session verdict (23 rounds): this kernel moves ~721 MB of halo-amplified
// vector-path traffic (587 MB reads at 4.4x amp + 134 MB writes) at ~7.2
// TB/s effective -- at/above the 6.29 TB/s demonstrated streaming ceiling,
// sustainable only via partial in-CU L1 hits. Cleanly tested levers:
// batch loads (+4%, kept), XCD swizzle (FETCH -> compulsory min, kept),
// v2f lanes (kept), v4f (neutral), LDS window staging (-20%), occupancy
// 16..73% (neutral), schedule pinning x3 (no-op), tile geometry for lower
// amp (TH=8 / w-split: 4 attempts, all voided by 2x register-balloon +
// spills -- allocator pathology unreachable from HIP source). The
// theoretical remaining ~30% (coincident-wave halo dedup) is real at the
// cache level (FETCH 66 MB observed) but not expressible without spills
// on this toolchain.
// ---------------------------------------------------------------------------
__global__ __launch_bounds__(256, 1)
void ppeg_conv(const float* __restrict__ x, const float* __restrict__ wt,
               const float* __restrict__ beff, float* __restrict__ out) {
#pragma clang fp contract(fast)
    const int tx = threadIdx.x;        // channel-pair lane 0..63
    const int ty = threadIdx.y;        // h-strip 0..3 (wave-uniform)

    // --- chunked XCD swizzle (XCD = linear id % 8, x fastest; bijective) ----
    const int L     = blockIdx.x + 32 * (blockIdx.y + 4 * blockIdx.z); // 0..2047
    const int g_lin = (L & 7) * 256 + (L >> 3);
    const int sp    = g_lin & 31;      // spatial block 0..31 within group
    const int g     = g_lin >> 5;      // 0..63 : (cblk, b) group
    const int cb    = (g & 3) * 128;
    const int b     = g >> 2;
    // ------------------------------------------------------------------------

    const int wblk  = sp & 7;
    const int hblk  = sp >> 3;
    const int oh0   = hblk * (TH * 4) + ty * TH;   // first of TH output rows
    const int wbase = wblk * TW;

    // Stage the block's 49x128 tap slab into LDS (once), coalesced.
    __shared__ float taps[49][128];
    const int tid = ty * 64 + tx;
    for (int idx = tid; idx < 49 * 128; idx += 256) {
        taps[idx >> 7][idx & 127] = wt[(idx >> 7) * Cc + cb + (idx & 127)];
    }
    __syncthreads();

    const int c0 = cb + 2 * tx;
    const float* xb = x + ((size_t)b * NTOK + 1) * Cc + c0;  // pixel (0,0)

    const v2f bias = *(const v2f*)&beff[c0];
    v2f acc[TH][TW];
#pragma unroll
    for (int o = 0; o < TH; ++o)
#pragma unroll
        for (int j = 0; j < TW; ++j) acc[o][j] = bias;

    // Stream input rows ir = oh0-3 .. oh0+TH+2. Row k feeds output rows
    // o in [k-6, k] (tap row r = k-o). All indices static after unroll.
#pragma unroll
    for (int k = 0; k < TH + 6; ++k) {
        const int ir = oh0 + k - 3;
        if (ir >= 0 && ir < Hh) {              // wave-uniform (oh0 fixed/wave)
            const float* xrow = xb + (size_t)ir * (Ww * Cc);
            v2f w[TW + 6];
            if (wblk == 0) {
                // slots 0-2 (pixels -3..-1) zero; slots 3-13 = pixels 0..10.
                const float* B0 = xrow + (size_t)2  * Cc;   // pixels 0..3
                const float* B1 = xrow + (size_t)6  * Cc;   // pixels 4..7
                const float* B2 = xrow + (size_t)10 * Cc;   // pixels 8..10
                w[0] = (v2f)(0.0f); w[1] = (v2f)(0.0f); w[2] = (v2f)(0.0f);
                asm volatile(
                    "global_load_dwordx2 %0,  %11, off offset:-4096\n\t"
                    "global_load_dwordx2 %1,  %11, off offset:-2048\n\t"
                    "global_load_dwordx2 %2,  %11, off offset:0\n\t"
                    "global_load_dwordx2 %3,  %11, off offset:2048\n\t"
                    "global_load_dwordx2 %4,  %12, off offset:-4096\n\t"
                    "global_load_dwordx2 %5,  %12, off offset:-2048\n\t"
                    "global_load_dwordx2 %6,  %12, off offset:0\n\t"
                    "global_load_dwordx2 %7,  %12, off offset:2048\n\t"
                    "global_load_dwordx2 %8,  %13, off offset:-4096\n\t"
                    "global_load_dwordx2 %9,  %13, off offset:-2048\n\t"
                    "global_load_dwordx2 %10, %13, off offset:0\n\t"
                    "s_waitcnt vmcnt(0)"
                    : "=&v"(w[3]), "=&v"(w[4]), "=&v"(w[5]), "=&v"(w[6]),
                      "=&v"(w[7]), "=&v"(w[8]), "=&v"(w[9]), "=&v"(w[10]),
                      "=&v"(w[11]), "=&v"(w[12]), "=&v"(w[13])
                    : "v"(B0), "v"(B1), "v"(B2));
            } else if (wblk == 7) {
                // slots 0-10 = pixels 53..63; slots 11-13 (64..66) zero.
                const float* B0 = xrow + (size_t)55 * Cc;   // pixels 53..56
                const float* B1 = xrow + (size_t)59 * Cc;   // pixels 57..60
                const float* B2 = xrow + (size_t)62 * Cc;   // pixels 61..63
                asm volatile(
                    "global_load_dwordx2 %0,  %11, off offset:-4096\n\t"
                    "global_load_dwordx2 %1,  %11, off offset:-2048\n\t"
                    "global_load_dwordx2 %2,  %11, off offset:0\n\t"
                    "global_load_dwordx2 %3,  %11, off offset:2048\n\t"
                    "global_load_dwordx2 %4,  %12, off offset:-4096\n\t"
                    "global_load_dwordx2 %5,  %12, off offset:-2048\n\t"
                    "global_load_dwordx2 %6,  %12, off offset:0\n\t"
                    "global_load_dwordx2 %7,  %12, off offset:2048\n\t"
                    "global_load_dwordx2 %8,  %13, off offset:-2048\n\t"
                    "global_load_dwordx2 %9,  %13, off offset:0\n\t"
                    "global_load_dwordx2 %10, %13, off offset:2048\n\t"
                    "s_waitcnt vmcnt(0)"
                    : "=&v"(w[0]), "=&v"(w[1]), "=&v"(w[2]), "=&v"(w[3]),
                      "=&v"(w[4]), "=&v"(w[5]), "=&v"(w[6]), "=&v"(w[7]),
                      "=&v"(w[8]), "=&v"(w[9]), "=&v"(w[10])
                    : "v"(B0), "v"(B1), "v"(B2));
                w[11] = (v2f)(0.0f); w[12] = (v2f)(0.0f); w[13] = (v2f)(0.0f);
            } else {
                // interior: slots 0-13 = pixels wbase-3 .. wbase+10.
                const float* B0 = xrow + (size_t)(wbase - 1)  * Cc;  // s0-3
                const float* B1 = xrow + (size_t)(wbase + 3)  * Cc;  // s4-7
                const float* B2 = xrow + (size_t)(wbase + 7)  * Cc;  // s8-11
                const float* B3 = xrow + (size_t)(wbase + 11) * Cc;  // s12-13
                asm volatile(
                    "global_load_dwordx2 %0,  %14, off offset:-4096\n\t"
                    "global_load_dwordx2 %1,  %14, off offset:-2048\n\t"
                    "global_load_dwordx2 %2,  %14, off offset:0\n\t"
                    "global_load_dwordx2 %3,  %14, off offset:2048\n\t"
                    "global_load_dwordx2 %4,  %15, off offset:-4096\n\t"
                    "global_load_dwordx2 %5,  %15, off offset:-2048\n\t"
                    "global_load_dwordx2 %6,  %15, off offset:0\n\t"
                    "global_load_dwordx2 %7,  %15, off offset:2048\n\t"
                    "global_load_dwordx2 %8,  %16, off offset:-4096\n\t"
                    "global_load_dwordx2 %9,  %16, off offset:-2048\n\t"
                    "global_load_dwordx2 %10, %16, off offset:0\n\t"
                    "global_load_dwordx2 %11, %16, off offset:2048\n\t"
                    "global_load_dwordx2 %12, %17, off offset:-4096\n\t"
                    "global_load_dwordx2 %13, %17, off offset:-2048\n\t"
                    "s_waitcnt vmcnt(0)"
                    : "=&v"(w[0]), "=&v"(w[1]), "=&v"(w[2]), "=&v"(w[3]),
                      "=&v"(w[4]), "=&v"(w[5]), "=&v"(w[6]), "=&v"(w[7]),
                      "=&v"(w[8]), "=&v"(w[9]), "=&v"(w[10]), "=&v"(w[11]),
                      "=&v"(w[12]), "=&v"(w[13])
                    : "v"(B0), "v"(B1), "v"(B2), "v"(B3));
            }
#pragma unroll
            for (int o = 0; o < TH; ++o) {
                if (o > k || o < k - 6) continue;   // static after unroll
                const int r = k - o;
#pragma unroll
                for (int s = 0; s < 7; ++s) {
                    const v2f tp = *(const v2f*)&taps[r * 7 + s][2 * tx];
#pragma unroll
                    for (int j = 0; j < TW; ++j)
                        acc[o][j] = tp * w[j + s] + acc[o][j];   // v_pk_fma_f32
                }
            }
        }
    }

#pragma unroll
    for (int o = 0; o < TH; ++o) {
        float* orow = out + ((size_t)b * NTOK + 1 + (size_t)(oh0 + o) * Ww + wbase) * Cc + c0;
#pragma unroll
        for (int j = 0; j < TW; ++j)
            __builtin_nontemporal_store(acc[o][j], (v2f*)(orow + (size_t)j * Cc));
    }
}

extern "C" void kernel_launch(void* const* d_in, const int* in_sizes, int n_in,
                              void* d_out, int out_size, void* d_ws, size_t ws_size,
                              hipStream_t stream) {
    const float* x  = (const float*)d_in[0];
    const float* w7 = (const float*)d_in[1];
    const float* b7 = (const float*)d_in[2];
    const float* w5 = (const float*)d_in[3];
    const float* b5 = (const float*)d_in[4];
    const float* w3 = (const float*)d_in[5];
    const float* b3 = (const float*)d_in[6];
    float* out = (float*)d_out;

    float* wt   = (float*)d_ws;          // 49*Cc floats, transposed [tap][channel]
    float* beff = wt + 49 * Cc;          // Cc floats

    ppeg_prep<<<(Cc * 49 + 255) / 256, 256, 0, stream>>>(w7, b7, w5, b5, w3, b3,
                                                         x, wt, beff, out);

    // (4 hblk x 8 wblk) x 4 cblk x 16 b = 2048 blocks of 256 threads.
    dim3 grid(32, Cc / 128, Bb);
    dim3 block(64, 4);
    ppeg_conv<<<grid, block, 0, stream>>>(x, wt, beff, out);
}